// Round 17
// baseline (253.147 us; speedup 1.0000x reference)
//
#include <hip/hip_runtime.h>
#include <hip/hip_bf16.h>

#define NU 4096
#define NI 4096
#define NE 262144
#define NPRED 65536
#define DD 64
#define KCL 1000
#define UNUM 50000
#define INUM 25000
#define INUM_PAD 25008
#define KCL_PAD 1008

typedef short sh8 __attribute__((ext_vector_type(8)));
typedef float f4 __attribute__((ext_vector_type(4)));

__device__ __forceinline__ float wred64(float x){
#pragma unroll
  for(int m=1;m<64;m<<=1) x += __shfl_xor(x,m);
  return x;
}

__device__ __forceinline__ float fast_exp2(float x){
  return __builtin_amdgcn_exp2f(x);
}

// ---- fused: degree histogram (blocks 0..1023) + static-table norms ----
#define HB 1024
#define HN0 (HB+12500)        // ntb_user  (50000 rows /4)
#define HN1 (HN0+6252)        // ntb_item  (25008 padded /4)
#define HN2 (HN1+252)         // ncb_u     (1008 padded /4)
#define HN3 (HN2+252)         // ncb_i     (1008 padded /4)

__global__ void k_histnorm(const int* __restrict__ eu, const int* __restrict__ ev,
                           int* cu, int* ci,
                           const float* __restrict__ emb_u, const float* __restrict__ emb_i,
                           const float* __restrict__ ucent, const float* __restrict__ icent,
                           __hip_bfloat16* ntb_u, __hip_bfloat16* ntb_i,
                           __hip_bfloat16* ncb_u, __hip_bfloat16* ncb_i){
  int b = blockIdx.x;
  if(b < HB){
    int t = b*256 + threadIdx.x;
    atomicAdd(&cu[eu[t]],1); atomicAdd(&ci[ev[t]],1);
    return;
  }
  const float* in; __hip_bfloat16* outp; int rows; int base;
  if(b < HN0)      { in=emb_u; outp=ntb_u; rows=UNUM; base=HB; }
  else if(b < HN1) { in=emb_i; outp=ntb_i; rows=INUM; base=HN0; }
  else if(b < HN2) { in=ucent; outp=ncb_u; rows=KCL;  base=HN1; }
  else             { in=icent; outp=ncb_i; rows=KCL;  base=HN2; }
  int row = (b-base)*4 + (threadIdx.x>>6);
  int lane = threadIdx.x & 63;
  if(row >= rows){ outp[row*DD + lane] = __float2bfloat16(0.f); return; }
  float v = in[row*DD + lane];
  float s = wred64(v*v);
  float sc = 1.0f / fmaxf(sqrtf(s), 1e-12f);
  outp[row*DD + lane] = __float2bfloat16(v*sc);
}

// ---- exclusive scan over 4096 counts (one block per side) + tot4 zeroing ----
__global__ void k_scan(const int* cnt_u, int* rp_u, int* cur_u, float* inv_u,
                       const int* cnt_i, int* rp_i, int* cur_i, float* inv_i,
                       float* tot4){
  {
    int base = blockIdx.x*8192 + threadIdx.x*8;
#pragma unroll
    for(int k=0;k<8;k++) tot4[base+k] = 0.f;
  }
  const int* cnt = blockIdx.x ? cnt_i : cnt_u;
  int* rp  = blockIdx.x ? rp_i  : rp_u;
  int* cur = blockIdx.x ? cur_i : cur_u;
  float* inv = blockIdx.x ? inv_i : inv_u;
  __shared__ int sdata[1024];
  int tid = threadIdx.x;
  int v[4]; int s = 0;
#pragma unroll
  for(int k=0;k<4;k++){ v[k]=cnt[tid*4+k]; s+=v[k]; }
  sdata[tid]=s; __syncthreads();
  for(int off=1; off<1024; off<<=1){
    int add = (tid>=off)? sdata[tid-off] : 0;
    __syncthreads();
    if(tid>=off) sdata[tid] += add;
    __syncthreads();
  }
  int run = sdata[tid]-s;   // exclusive base
#pragma unroll
  for(int k=0;k<4;k++){
    int idx = tid*4+k;
    rp[idx]=run; cur[idx]=run;
    inv[idx] = 1.0f/sqrtf(fmaxf((float)v[k],1.0f));
    run += v[k];
  }
  if(tid==1023) rp[4096]=run;
}

// ---- fused CSR fill (blocks 0..1023) + gather/init (blocks 1024..3071) ----
__global__ void k_fillgather(const int* __restrict__ eu, const int* __restrict__ ev,
                             int* cur_u, int* cur_i, int* adj_u, int* adj_i,
                             const float* __restrict__ emb_u, const float* __restrict__ emb_i,
                             const int* __restrict__ idx_u, const int* __restrict__ idx_i,
                             const float* __restrict__ inv_u, const float* __restrict__ inv_i,
                             float* e_u, float* e_i, float* res_u, float* res_i,
                             float* hs_u, float* hs_i){
  int b = blockIdx.x;
  if(b < 1024){
    int t = b*256 + threadIdx.x;
    int u=eu[t], v=ev[t];
    adj_u[atomicAdd(&cur_u[u],1)] = v;
    adj_i[atomicAdd(&cur_i[v],1)] = u;
  } else {
    int t = (b-1024)*256 + threadIdx.x;
    const int half = NU*DD;
    if(t < half){
      int r=t>>6;
      float v = emb_u[idx_u[r]*DD + (t&63)];
      e_u[t]=v; res_u[t]=v; hs_u[t]=v*inv_u[r];
    } else {
      int s=t-half; int r=s>>6;
      float v = emb_i[idx_i[r]*DD + (s&63)];
      e_i[s]=v; res_i[s]=v; hs_i[s]=v*inv_i[r];
    }
  }
}

// ---- pull-style conv: 4 waves per block, one node per wave ----
// adj content differs call-to-call (atomic fill order), so adj MUST be read
// through the vector path (coalesced per-lane load + shfl broadcast), never
// scalar s_load (K$ staleness across graph replays = nondeterministic output).
// last=1 (layer 3): fused epilogue computes nc (SC*normalize(h)),
// npv (SC*normalize(e)) and this side's pos4 entries; skips hs_next write.
__global__ void k_conv(const int* __restrict__ rp_i, const int* __restrict__ adj_i,
                       const float* __restrict__ hsu_in, const float* __restrict__ inv_i,
                       float* h_i, float* res_i, float* hsi_out,
                       const int* __restrict__ rp_u, const int* __restrict__ adj_u,
                       const float* __restrict__ hsi_in, const float* __restrict__ inv_u,
                       float* h_u, float* res_u, float* hsu_out,
                       const float* __restrict__ e_u, const float* __restrict__ e_i,
                       const float* __restrict__ ucent, const float* __restrict__ icent,
                       const int* __restrict__ idx_u, const int* __restrict__ idx_i,
                       const int* __restrict__ u2c, const int* __restrict__ i2c,
                       __hip_bfloat16* nc_u, __hip_bfloat16* nc_i,
                       __hip_bfloat16* npv_u, __hip_bfloat16* npv_i,
                       float* pos4, int last){
  int b = blockIdx.x*4 + (threadIdx.x>>6);
  int lane = threadIdx.x & 63;
  const int* rp; const int* adj; const float* srcv; const float* inv;
  float *h, *res, *hso; int node;
  const float* eX; const float* cent; const int* idxX; const int* n2c;
  __hip_bfloat16 *nc, *npv; float *posA, *posB;
  if(b < NI){
    rp=rp_i; adj=adj_i; srcv=hsu_in; inv=inv_i; h=h_i; res=res_i; hso=hsi_out; node=b;
    eX=e_i; cent=icent; idxX=idx_i; n2c=i2c; nc=nc_i; npv=npv_i;
    posA=pos4+1*NU; posB=pos4+3*NU;
  } else {
    node=b-NI; rp=rp_u; adj=adj_u; srcv=hsi_in; inv=inv_u; h=h_u; res=res_u; hso=hsu_out;
    eX=e_u; cent=ucent; idxX=idx_u; n2c=u2c; nc=nc_u; npv=npv_u;
    posA=pos4+0*NU; posB=pos4+2*NU;
  }
  int s=rp[node], e=rp[node+1];
  float acc=0.f;
  for(int base=s; base<e; base+=64){
    int m = e-base;
    int myidx = adj[base + min(lane, m-1)];   // one coalesced vector load / 64 edges
    int kk = min(64, m);
    int k=0;
    for(; k+8<=kk; k+=8){
      int i0=__shfl(myidx,k  ), i1=__shfl(myidx,k+1),
          i2=__shfl(myidx,k+2), i3=__shfl(myidx,k+3),
          i4=__shfl(myidx,k+4), i5=__shfl(myidx,k+5),
          i6=__shfl(myidx,k+6), i7=__shfl(myidx,k+7);
      float v0=srcv[i0*DD+lane], v1=srcv[i1*DD+lane],
            v2=srcv[i2*DD+lane], v3=srcv[i3*DD+lane],
            v4=srcv[i4*DD+lane], v5=srcv[i5*DD+lane],
            v6=srcv[i6*DD+lane], v7=srcv[i7*DD+lane];
      acc += ((v0+v1)+(v2+v3)) + ((v4+v5)+(v6+v7));
    }
    for(; k<kk; k++) acc += srcv[__shfl(myidx,k)*DD+lane];
  }
  float iv = inv[node];
  float outv = acc*iv;
  h[node*DD+lane] = outv;
  res[node*DD+lane] += outv;
  if(!last){
    hso[node*DD+lane] = outv*iv;
    return;
  }
  // ---- fused epilogue (layer 3): norms + pos dots ----
  const float SC = 14.426950408889634f;
  const float eps = 1e-12f;
  float ev = eX[node*DD+lane];
  float hn = wred64(outv*outv);
  float en = wred64(ev*ev);
  float ihn = 1.0f/fmaxf(sqrtf(hn), eps);
  float ien = 1.0f/fmaxf(sqrtf(en), eps);
  nc [node*DD+lane] = __float2bfloat16(outv*(SC*ihn));
  npv[node*DD+lane] = __float2bfloat16(ev  *(SC*ien));
  int c = n2c[idxX[node]];
  float cv = cent[c*DD+lane];
  float he = wred64(outv*ev);
  float cc = wred64(cv*cv);
  float ec = wred64(ev*cv);
  if(lane==0){
    float icn = 1.0f/fmaxf(sqrtf(cc), eps);
    posA[node] = he*ihn*ien;
    posB[node] = ec*ien*icn;
  }
}

// ---- fused MFMA exp-sum + scores + last-block loss; flat exact grid ----
// Blocks: [0,784) user, [784,1176) item, [1176,1344) protoU, [1344,1512)
// protoI, [1512,2296) scores. Within a segment, XCD-pinned decode:
// local -> (g=local/64, r=local%64), y=8g+(r&7), x=r>>3 (idle if y>=ny —
// still counted). Every block increments ctr after threadfence; the 2296th
// runs the loss inline (tot4 read with agent-scope atomic loads).
// tot[b] += sum_j exp2(dot(A[b],B[j])), A pre-scaled by SC = 10*log2(e).
// B buffers have >=48 rows of slack past nBpad (depth-1 prefetch overrun).
struct EArg {
  const __hip_bfloat16* A; const __hip_bfloat16* B; float* tot;
  int nBpad; int jchunk; int ny;
};
struct LArg {
  const float* res_u; const float* res_i;
  const int* pu; const int* pv; const int* nu; const int* nv;
  float* out; float* tot4; const float* pos4; unsigned* ctr;
};
#define EB0 784
#define EB1 (EB0+392)
#define EB2 (EB1+168)
#define EB3 (EB2+168)      // 1512 compute blocks
#define EBT (EB3+784)      // + 784 score blocks = 2296 total

__global__ __launch_bounds__(256,4)
void k_expsum(EArg e0, EArg e1, EArg e2, EArg e3, LArg lc){
  int bid = blockIdx.x;
  int tid = threadIdx.x;
  if(bid >= EB3){
    // ---- scores: 16 lanes per pair, grid-stride ----
    const int stride = (EBT-EB3)*256;
    const int limit = 2*NPRED*16;
    for(int t = (bid-EB3)*256 + tid; t < limit; t += stride){
      int pair = t >> 4;
      int sl = t & 15;
      int a,b;
      if(pair < NPRED){ a=lc.pu[pair]; b=lc.pv[pair]; }
      else { a=lc.nu[pair-NPRED]; b=lc.nv[pair-NPRED]; }
      f4 xu = *(const f4*)(lc.res_u + a*DD + sl*4);
      f4 xv = *(const f4*)(lc.res_i + b*DD + sl*4);
      float x = xu[0]*xv[0] + xu[1]*xv[1] + xu[2]*xv[2] + xu[3]*xv[3];
      x += __shfl_xor(x,1); x += __shfl_xor(x,2);
      x += __shfl_xor(x,4); x += __shfl_xor(x,8);
      if(sl==0) lc.out[pair] = x*(1.0f/16.0f);  // res divided by 4 each side
    }
  } else {
    EArg e; int local;
    if(bid < EB0)      { e = e0; local = bid; }
    else if(bid < EB1) { e = e1; local = bid-EB0; }
    else if(bid < EB2) { e = e2; local = bid-EB1; }
    else               { e = e3; local = bid-EB2; }
    int g = local >> 6, r6 = local & 63;
    int y = 8*g + (r6 & 7);
    int x = r6 >> 3;
    if(y < e.ny){
      int wave = tid >> 6;
      int lane = tid & 63;
      int row0 = (x*4 + wave)*128;
      int j_begin = y*e.jchunk;
      int j_end = min(j_begin + e.jchunk, e.nBpad);
      int r = lane & 15, kq = (lane>>4)*8;

      sh8 a0[8], a1[8];
#pragma unroll
      for(int t=0;t<8;t++){
        const short* ap = (const short*)(e.A + (row0 + t*16 + r)*DD);
        a0[t] = *(const sh8*)(ap + kq);
        a1[t] = *(const sh8*)(ap + kq + 32);
      }
      float acc[8][4];
#pragma unroll
      for(int t=0;t<8;t++)
#pragma unroll
        for(int q=0;q<4;q++) acc[t][q]=0.f;

      const short* bbase = (const short*)e.B;
      const short* bp0 = bbase + (j_begin + r)*DD + kq;
      sh8 b0 = *(const sh8*)(bp0);
      sh8 b1 = *(const sh8*)(bp0 + 32);

#pragma unroll 2
      for(int j0=j_begin; j0<j_end; j0+=16){
        const short* np = bbase + (j0 + 16 + r)*DD + kq;   // prefetch next tile
        sh8 n0 = *(const sh8*)(np);
        sh8 n1 = *(const sh8*)(np + 32);
#pragma unroll
        for(int t=0;t<8;t++){
          f4 c = {0.f,0.f,0.f,0.f};
          c = __builtin_amdgcn_mfma_f32_16x16x32_bf16(a0[t], b0, c, 0,0,0);
          c = __builtin_amdgcn_mfma_f32_16x16x32_bf16(a1[t], b1, c, 0,0,0);
#pragma unroll
          for(int q=0;q<4;q++) acc[t][q] += fast_exp2(c[q]);
        }
        b0 = n0; b1 = n1;
      }
#pragma unroll
      for(int t=0;t<8;t++){
#pragma unroll
        for(int q=0;q<4;q++){
          float v = acc[t][q];
          v += __shfl_xor(v,1); v += __shfl_xor(v,2);
          v += __shfl_xor(v,4); v += __shfl_xor(v,8);
          if(r==0) atomicAdd(&e.tot[row0 + t*16 + (lane>>4)*4 + q], v);
        }
      }
    }
  }
  // ---- completion counter; last block computes losses ----
  __shared__ int s_done;
  if(tid == 0){
    __threadfence();
    unsigned old = atomicAdd(lc.ctr, 1u);
    s_done = (old == (unsigned)(EBT-1)) ? 1 : 0;
  }
  __syncthreads();
  if(s_done){
    const float PI_ = (float)(INUM_PAD-INUM);   // 8
    const float PK_ = (float)(KCL_PAD-KCL);     // 8
    float* tot4 = lc.tot4;
    const float* pos4 = lc.pos4;
    float s0=0,s1=0,s2=0,s3=0;
    for(int b=tid; b<NU; b+=256){
      float t0 = __hip_atomic_load(&tot4[0*NU+b], __ATOMIC_RELAXED, __HIP_MEMORY_SCOPE_AGENT);
      float t1 = __hip_atomic_load(&tot4[1*NU+b], __ATOMIC_RELAXED, __HIP_MEMORY_SCOPE_AGENT);
      float t2 = __hip_atomic_load(&tot4[2*NU+b], __ATOMIC_RELAXED, __HIP_MEMORY_SCOPE_AGENT);
      float t3 = __hip_atomic_load(&tot4[3*NU+b], __ATOMIC_RELAXED, __HIP_MEMORY_SCOPE_AGENT);
      s0 += logf(t0)       - 10.f*pos4[0*NU+b];
      s1 += logf(t1 - PI_) - 10.f*pos4[1*NU+b];
      s2 += logf(t2 - PK_) - 10.f*pos4[2*NU+b];
      s3 += logf(t3 - PK_) - 10.f*pos4[3*NU+b];
    }
    s0=wred64(s0); s1=wred64(s1); s2=wred64(s2); s3=wred64(s3);
    __shared__ float ls[4][4];
    int lane=tid&63, w=tid>>6;
    if(lane==0){ ls[w][0]=s0; ls[w][1]=s1; ls[w][2]=s2; ls[w][3]=s3; }
    __syncthreads();
    if(tid==0){
      float a=0,b2=0,c=0,d=0;
#pragma unroll
      for(int k=0;k<4;k++){ a+=ls[k][0]; b2+=ls[k][1]; c+=ls[k][2]; d+=ls[k][3]; }
      lc.out[2*NPRED]   = 1e-6f*(a+b2);
      lc.out[2*NPRED+1] = 8e-8f*(c+d);
    }
  }
}

extern "C" void kernel_launch(void* const* d_in, const int* in_sizes, int n_in,
                              void* d_out, int out_size, void* d_ws, size_t ws_size,
                              hipStream_t stream) {
  const float* emb_user = (const float*)d_in[0];
  const float* emb_item = (const float*)d_in[1];
  const float* ucent    = (const float*)d_in[2];
  const float* icent    = (const float*)d_in[3];
  const int* edge_u = (const int*)d_in[4];
  const int* edge_v = (const int*)d_in[5];
  const int* pos_u  = (const int*)d_in[6];
  const int* pos_v  = (const int*)d_in[7];
  const int* neg_u  = (const int*)d_in[8];
  const int* neg_v  = (const int*)d_in[9];
  const int* idx_u  = (const int*)d_in[10];
  const int* idx_i  = (const int*)d_in[11];
  const int* u2c    = (const int*)d_in[12];
  const int* i2c    = (const int*)d_in[13];
  float* out = (float*)d_out;

  char* w = (char*)d_ws;
  auto alloc = [&](size_t bytes)->void*{
    void* p = (void*)w;
    w += (bytes + 255) & ~(size_t)255;
    return p;
  };
  int* cnt_u = (int*)alloc(NU*4);            // cnt_u+cnt_i+ctr: one memset
  int* cnt_i = (int*)alloc(NI*4);
  unsigned* ctr = (unsigned*)alloc(256);
  int* rp_u  = (int*)alloc((NU+1)*4);
  int* rp_i  = (int*)alloc((NI+1)*4);
  int* cur_u = (int*)alloc(NU*4);
  int* cur_i = (int*)alloc(NI*4);
  int* adj_u = (int*)alloc((size_t)NE*4);
  int* adj_i = (int*)alloc((size_t)NE*4);
  float* inv_u = (float*)alloc(NU*4);
  float* inv_i = (float*)alloc(NI*4);
  float* e_u  = (float*)alloc((size_t)NU*DD*4);
  float* e_i  = (float*)alloc((size_t)NI*DD*4);
  float* h_u  = (float*)alloc((size_t)NU*DD*4);
  float* h_i  = (float*)alloc((size_t)NI*DD*4);
  float* hsA_u = (float*)alloc((size_t)NU*DD*4);
  float* hsA_i = (float*)alloc((size_t)NI*DD*4);
  float* hsB_u = (float*)alloc((size_t)NU*DD*4);
  float* hsB_i = (float*)alloc((size_t)NI*DD*4);
  float* res_u= (float*)alloc((size_t)NU*DD*4);
  float* res_i= (float*)alloc((size_t)NI*DD*4);
  // B-side bf16 buffers: +48 rows slack for depth-1 prefetch overrun
  __hip_bfloat16* ntb_user = (__hip_bfloat16*)alloc((size_t)(UNUM+48)*DD*2);
  __hip_bfloat16* ntb_item = (__hip_bfloat16*)alloc((size_t)(INUM_PAD+48)*DD*2);
  __hip_bfloat16* ncb_u = (__hip_bfloat16*)alloc((size_t)(KCL_PAD+48)*DD*2);
  __hip_bfloat16* ncb_i = (__hip_bfloat16*)alloc((size_t)(KCL_PAD+48)*DD*2);
  __hip_bfloat16* nc_u  = (__hip_bfloat16*)alloc((size_t)NU*DD*2);
  __hip_bfloat16* nc_i  = (__hip_bfloat16*)alloc((size_t)NI*DD*2);
  __hip_bfloat16* npv_u = (__hip_bfloat16*)alloc((size_t)NU*DD*2);
  __hip_bfloat16* npv_i = (__hip_bfloat16*)alloc((size_t)NI*DD*2);
  float* tot4 = (float*)alloc(4*NU*4);
  float* pos4 = (float*)alloc(4*NU*4);

  hipMemsetAsync(cnt_u, 0, 2*NU*4 + 256, stream);  // cnt_u+cnt_i+ctr contiguous

  k_histnorm<<<HN3, 256, 0, stream>>>(edge_u, edge_v, cnt_u, cnt_i,
                                      emb_user, emb_item, ucent, icent,
                                      ntb_user, ntb_item, ncb_u, ncb_i);
  k_scan<<<2, 1024, 0, stream>>>(cnt_u, rp_u, cur_u, inv_u,
                                 cnt_i, rp_i, cur_i, inv_i, tot4);
  k_fillgather<<<3072, 256, 0, stream>>>(edge_u, edge_v, cur_u, cur_i, adj_u, adj_i,
                                         emb_user, emb_item, idx_u, idx_i,
                                         inv_u, inv_i,
                                         e_u, e_i, res_u, res_i, hsA_u, hsA_i);
  // layer 0: read A write B; layer 1: B->A; layer 2 (last): A->(h,res,norms,pos)
  k_conv<<<(NU+NI)/4, 256, 0, stream>>>(rp_i, adj_i, hsA_u, inv_i, h_i, res_i, hsB_i,
                                        rp_u, adj_u, hsA_i, inv_u, h_u, res_u, hsB_u,
                                        e_u, e_i, ucent, icent, idx_u, idx_i, u2c, i2c,
                                        nc_u, nc_i, npv_u, npv_i, pos4, 0);
  k_conv<<<(NU+NI)/4, 256, 0, stream>>>(rp_i, adj_i, hsB_u, inv_i, h_i, res_i, hsA_i,
                                        rp_u, adj_u, hsB_i, inv_u, h_u, res_u, hsA_u,
                                        e_u, e_i, ucent, icent, idx_u, idx_i, u2c, i2c,
                                        nc_u, nc_i, npv_u, npv_i, pos4, 0);
  k_conv<<<(NU+NI)/4, 256, 0, stream>>>(rp_i, adj_i, hsA_u, inv_i, h_i, res_i, hsB_i,
                                        rp_u, adj_u, hsA_i, inv_u, h_u, res_u, hsB_u,
                                        e_u, e_i, ucent, icent, idx_u, idx_i, u2c, i2c,
                                        nc_u, nc_i, npv_u, npv_i, pos4, 1);

  // fused exp-sum + scores + last-block loss
  EArg eu_ = { nc_u,  ntb_user, tot4 + 0*NU, UNUM,     512, 98 };
  EArg ei_ = { nc_i,  ntb_item, tot4 + 1*NU, INUM_PAD, 512, 49 };
  EArg ep0 = { npv_u, ncb_u,    tot4 + 2*NU, KCL_PAD,  48,  21 };
  EArg ep1 = { npv_i, ncb_i,    tot4 + 3*NU, KCL_PAD,  48,  21 };
  LArg lc  = { res_u, res_i, pos_u, pos_v, neg_u, neg_v, out, tot4, pos4, ctr };
  k_expsum<<<EBT, 256, 0, stream>>>(eu_, ei_, ep0, ep1, lc);
}

// Round 18
// 211.957 us; speedup vs baseline: 1.1943x; 1.1943x over previous
//
#include <hip/hip_runtime.h>
#include <hip/hip_bf16.h>

#define NU 4096
#define NI 4096
#define NE 262144
#define NPRED 65536
#define DD 64
#define KCL 1000
#define UNUM 50000
#define INUM 25000
#define INUM_PAD 25008
#define KCL_PAD 1008

typedef short sh8 __attribute__((ext_vector_type(8)));
typedef float f4 __attribute__((ext_vector_type(4)));

__device__ __forceinline__ float wred64(float x){
#pragma unroll
  for(int m=1;m<64;m<<=1) x += __shfl_xor(x,m);
  return x;
}

__device__ __forceinline__ float fast_exp2(float x){
  return __builtin_amdgcn_exp2f(x);
}

// ---- fused: degree histogram (blocks 0..1023) + static-table norms ----
#define HB 1024
#define HN0 (HB+12500)        // ntb_user  (50000 rows /4)
#define HN1 (HN0+6252)        // ntb_item  (25008 padded /4)
#define HN2 (HN1+252)         // ncb_u     (1008 padded /4)
#define HN3 (HN2+252)         // ncb_i     (1008 padded /4)

__global__ void k_histnorm(const int* __restrict__ eu, const int* __restrict__ ev,
                           int* cu, int* ci,
                           const float* __restrict__ emb_u, const float* __restrict__ emb_i,
                           const float* __restrict__ ucent, const float* __restrict__ icent,
                           __hip_bfloat16* ntb_u, __hip_bfloat16* ntb_i,
                           __hip_bfloat16* ncb_u, __hip_bfloat16* ncb_i){
  int b = blockIdx.x;
  if(b < HB){
    int t = b*256 + threadIdx.x;
    atomicAdd(&cu[eu[t]],1); atomicAdd(&ci[ev[t]],1);
    return;
  }
  const float* in; __hip_bfloat16* outp; int rows; int base;
  if(b < HN0)      { in=emb_u; outp=ntb_u; rows=UNUM; base=HB; }
  else if(b < HN1) { in=emb_i; outp=ntb_i; rows=INUM; base=HN0; }
  else if(b < HN2) { in=ucent; outp=ncb_u; rows=KCL;  base=HN1; }
  else             { in=icent; outp=ncb_i; rows=KCL;  base=HN2; }
  int row = (b-base)*4 + (threadIdx.x>>6);
  int lane = threadIdx.x & 63;
  if(row >= rows){ outp[row*DD + lane] = __float2bfloat16(0.f); return; }
  float v = in[row*DD + lane];
  float s = wred64(v*v);
  float sc = 1.0f / fmaxf(sqrtf(s), 1e-12f);
  outp[row*DD + lane] = __float2bfloat16(v*sc);
}

// ---- exclusive scan over 4096 counts (one block per side) + tot4 zeroing ----
__global__ void k_scan(const int* cnt_u, int* rp_u, int* cur_u, float* inv_u,
                       const int* cnt_i, int* rp_i, int* cur_i, float* inv_i,
                       float* tot4){
  {
    int base = blockIdx.x*8192 + threadIdx.x*8;
#pragma unroll
    for(int k=0;k<8;k++) tot4[base+k] = 0.f;
  }
  const int* cnt = blockIdx.x ? cnt_i : cnt_u;
  int* rp  = blockIdx.x ? rp_i  : rp_u;
  int* cur = blockIdx.x ? cur_i : cur_u;
  float* inv = blockIdx.x ? inv_i : inv_u;
  __shared__ int sdata[1024];
  int tid = threadIdx.x;
  int v[4]; int s = 0;
#pragma unroll
  for(int k=0;k<4;k++){ v[k]=cnt[tid*4+k]; s+=v[k]; }
  sdata[tid]=s; __syncthreads();
  for(int off=1; off<1024; off<<=1){
    int add = (tid>=off)? sdata[tid-off] : 0;
    __syncthreads();
    if(tid>=off) sdata[tid] += add;
    __syncthreads();
  }
  int run = sdata[tid]-s;   // exclusive base
#pragma unroll
  for(int k=0;k<4;k++){
    int idx = tid*4+k;
    rp[idx]=run; cur[idx]=run;
    inv[idx] = 1.0f/sqrtf(fmaxf((float)v[k],1.0f));
    run += v[k];
  }
  if(tid==1023) rp[4096]=run;
}

// ---- fused CSR fill (blocks 0..1023) + gather/init (blocks 1024..3071) ----
__global__ void k_fillgather(const int* __restrict__ eu, const int* __restrict__ ev,
                             int* cur_u, int* cur_i, int* adj_u, int* adj_i,
                             const float* __restrict__ emb_u, const float* __restrict__ emb_i,
                             const int* __restrict__ idx_u, const int* __restrict__ idx_i,
                             const float* __restrict__ inv_u, const float* __restrict__ inv_i,
                             float* e_u, float* e_i, float* res_u, float* res_i,
                             float* hs_u, float* hs_i){
  int b = blockIdx.x;
  if(b < 1024){
    int t = b*256 + threadIdx.x;
    int u=eu[t], v=ev[t];
    adj_u[atomicAdd(&cur_u[u],1)] = v;
    adj_i[atomicAdd(&cur_i[v],1)] = u;
  } else {
    int t = (b-1024)*256 + threadIdx.x;
    const int half = NU*DD;
    if(t < half){
      int r=t>>6;
      float v = emb_u[idx_u[r]*DD + (t&63)];
      e_u[t]=v; res_u[t]=v; hs_u[t]=v*inv_u[r];
    } else {
      int s=t-half; int r=s>>6;
      float v = emb_i[idx_i[r]*DD + (s&63)];
      e_i[s]=v; res_i[s]=v; hs_i[s]=v*inv_i[r];
    }
  }
}

// ---- pull-style conv: 4 waves per block, one node per wave ----
// adj content differs call-to-call (atomic fill order), so adj MUST be read
// through the vector path (coalesced per-lane load + shfl broadcast), never
// scalar s_load (K$ staleness across graph replays = nondeterministic output).
// last=1 (layer 3): fused epilogue computes nc (SC*normalize(h)),
// npv (SC*normalize(e)) and this side's pos4 entries; skips hs_next write.
__global__ void k_conv(const int* __restrict__ rp_i, const int* __restrict__ adj_i,
                       const float* __restrict__ hsu_in, const float* __restrict__ inv_i,
                       float* h_i, float* res_i, float* hsi_out,
                       const int* __restrict__ rp_u, const int* __restrict__ adj_u,
                       const float* __restrict__ hsi_in, const float* __restrict__ inv_u,
                       float* h_u, float* res_u, float* hsu_out,
                       const float* __restrict__ e_u, const float* __restrict__ e_i,
                       const float* __restrict__ ucent, const float* __restrict__ icent,
                       const int* __restrict__ idx_u, const int* __restrict__ idx_i,
                       const int* __restrict__ u2c, const int* __restrict__ i2c,
                       __hip_bfloat16* nc_u, __hip_bfloat16* nc_i,
                       __hip_bfloat16* npv_u, __hip_bfloat16* npv_i,
                       float* pos4, int last){
  int b = blockIdx.x*4 + (threadIdx.x>>6);
  int lane = threadIdx.x & 63;
  const int* rp; const int* adj; const float* srcv; const float* inv;
  float *h, *res, *hso; int node;
  const float* eX; const float* cent; const int* idxX; const int* n2c;
  __hip_bfloat16 *nc, *npv; float *posA, *posB;
  if(b < NI){
    rp=rp_i; adj=adj_i; srcv=hsu_in; inv=inv_i; h=h_i; res=res_i; hso=hsi_out; node=b;
    eX=e_i; cent=icent; idxX=idx_i; n2c=i2c; nc=nc_i; npv=npv_i;
    posA=pos4+1*NU; posB=pos4+3*NU;
  } else {
    node=b-NI; rp=rp_u; adj=adj_u; srcv=hsi_in; inv=inv_u; h=h_u; res=res_u; hso=hsu_out;
    eX=e_u; cent=ucent; idxX=idx_u; n2c=u2c; nc=nc_u; npv=npv_u;
    posA=pos4+0*NU; posB=pos4+2*NU;
  }
  int s=rp[node], e=rp[node+1];
  float acc=0.f;
  for(int base=s; base<e; base+=64){
    int m = e-base;
    int myidx = adj[base + min(lane, m-1)];   // one coalesced vector load / 64 edges
    int kk = min(64, m);
    int k=0;
    for(; k+8<=kk; k+=8){
      int i0=__shfl(myidx,k  ), i1=__shfl(myidx,k+1),
          i2=__shfl(myidx,k+2), i3=__shfl(myidx,k+3),
          i4=__shfl(myidx,k+4), i5=__shfl(myidx,k+5),
          i6=__shfl(myidx,k+6), i7=__shfl(myidx,k+7);
      float v0=srcv[i0*DD+lane], v1=srcv[i1*DD+lane],
            v2=srcv[i2*DD+lane], v3=srcv[i3*DD+lane],
            v4=srcv[i4*DD+lane], v5=srcv[i5*DD+lane],
            v6=srcv[i6*DD+lane], v7=srcv[i7*DD+lane];
      acc += ((v0+v1)+(v2+v3)) + ((v4+v5)+(v6+v7));
    }
    for(; k<kk; k++) acc += srcv[__shfl(myidx,k)*DD+lane];
  }
  float iv = inv[node];
  float outv = acc*iv;
  h[node*DD+lane] = outv;
  res[node*DD+lane] += outv;
  if(!last){
    hso[node*DD+lane] = outv*iv;
    return;
  }
  // ---- fused epilogue (layer 3): norms + pos dots ----
  const float SC = 14.426950408889634f;
  const float eps = 1e-12f;
  float ev = eX[node*DD+lane];
  float hn = wred64(outv*outv);
  float en = wred64(ev*ev);
  float ihn = 1.0f/fmaxf(sqrtf(hn), eps);
  float ien = 1.0f/fmaxf(sqrtf(en), eps);
  nc [node*DD+lane] = __float2bfloat16(outv*(SC*ihn));
  npv[node*DD+lane] = __float2bfloat16(ev  *(SC*ien));
  int c = n2c[idxX[node]];
  float cv = cent[c*DD+lane];
  float he = wred64(outv*ev);
  float cc = wred64(cv*cv);
  float ec = wred64(ev*cv);
  if(lane==0){
    float icn = 1.0f/fmaxf(sqrtf(cc), eps);
    posA[node] = he*ihn*ien;
    posB[node] = ec*ien*icn;
  }
}

// ---- fused MFMA exp-sum (z=0..3) + scores (z=4); 128 A-rows per wave ----
// EXACT R16-bench structure (best measured: 78.7us expsum, 217.4 total).
// jchunk=512 -> 1208 working blocks. XCD-pinned decomposition:
// bid -> (g=bid/64, r=bid%64), y=8g+(r&7), x=r>>3; all 8 x-blocks of a
// B-chunk share bid%8 -> same XCD -> chunk L2-resident.
// z=4 runs the pos/neg score pairs (memory-bound, backfills expsum drain).
// tot[b] += sum_j exp2(dot(A[b],B[j])), A pre-scaled by SC = 10*log2(e).
// B buffers have >=48 rows of slack past nBpad (depth-1 prefetch overrun).
struct EArg {
  const __hip_bfloat16* A; const __hip_bfloat16* B; float* tot;
  int nBpad; int jchunk; int ny;
};
struct SArg {
  const float* res_u; const float* res_i;
  const int* pu; const int* pv; const int* nu; const int* nv; float* out;
};
#define EGX 784

__global__ __launch_bounds__(256,4)
void k_expsum(EArg e0, EArg e1, EArg e2, EArg e3, SArg sc){
  if(blockIdx.z == 4){
    // ---- scores: 16 lanes per pair, grid-stride ----
    const int stride = EGX*256;
    const int limit = 2*NPRED*16;
    for(int t = blockIdx.x*256 + threadIdx.x; t < limit; t += stride){
      int pair = t >> 4;
      int sl = t & 15;
      int a,b;
      if(pair < NPRED){ a=sc.pu[pair]; b=sc.pv[pair]; }
      else { a=sc.nu[pair-NPRED]; b=sc.nv[pair-NPRED]; }
      f4 xu = *(const f4*)(sc.res_u + a*DD + sl*4);
      f4 xv = *(const f4*)(sc.res_i + b*DD + sl*4);
      float x = xu[0]*xv[0] + xu[1]*xv[1] + xu[2]*xv[2] + xu[3]*xv[3];
      x += __shfl_xor(x,1); x += __shfl_xor(x,2);
      x += __shfl_xor(x,4); x += __shfl_xor(x,8);
      if(sl==0) sc.out[pair] = x*(1.0f/16.0f);  // res divided by 4 each side
    }
    return;
  }
  EArg e = (blockIdx.z==0)? e0 : (blockIdx.z==1)? e1 : (blockIdx.z==2)? e2 : e3;
  int bid = blockIdx.x;
  int g = bid >> 6, r6 = bid & 63;
  int y = 8*g + (r6 & 7);
  int x = r6 >> 3;
  if(y >= e.ny) return;
  int wave = threadIdx.x >> 6;
  int lane = threadIdx.x & 63;
  int row0 = (x*4 + wave)*128;
  int j_begin = y*e.jchunk;
  int j_end = min(j_begin + e.jchunk, e.nBpad);
  int r = lane & 15, kq = (lane>>4)*8;

  sh8 a0[8], a1[8];
#pragma unroll
  for(int t=0;t<8;t++){
    const short* ap = (const short*)(e.A + (row0 + t*16 + r)*DD);
    a0[t] = *(const sh8*)(ap + kq);
    a1[t] = *(const sh8*)(ap + kq + 32);
  }
  float acc[8][4];
#pragma unroll
  for(int t=0;t<8;t++)
#pragma unroll
    for(int q=0;q<4;q++) acc[t][q]=0.f;

  const short* bbase = (const short*)e.B;
  const short* bp0 = bbase + (j_begin + r)*DD + kq;
  sh8 b0 = *(const sh8*)(bp0);
  sh8 b1 = *(const sh8*)(bp0 + 32);

#pragma unroll 2
  for(int j0=j_begin; j0<j_end; j0+=16){
    const short* np = bbase + (j0 + 16 + r)*DD + kq;   // prefetch next tile
    sh8 n0 = *(const sh8*)(np);
    sh8 n1 = *(const sh8*)(np + 32);
#pragma unroll
    for(int t=0;t<8;t++){
      f4 c = {0.f,0.f,0.f,0.f};
      c = __builtin_amdgcn_mfma_f32_16x16x32_bf16(a0[t], b0, c, 0,0,0);
      c = __builtin_amdgcn_mfma_f32_16x16x32_bf16(a1[t], b1, c, 0,0,0);
#pragma unroll
      for(int q=0;q<4;q++) acc[t][q] += fast_exp2(c[q]);
    }
    b0 = n0; b1 = n1;
  }
#pragma unroll
  for(int t=0;t<8;t++){
#pragma unroll
    for(int q=0;q<4;q++){
      float v = acc[t][q];
      v += __shfl_xor(v,1); v += __shfl_xor(v,2);
      v += __shfl_xor(v,4); v += __shfl_xor(v,8);
      if(r==0) atomicAdd(&e.tot[row0 + t*16 + (lane>>4)*4 + q], v);
    }
  }
}

// ---- final losses (pad rows each contributed exp2(0)=1 -> subtract) ----
__global__ void k_loss(const float* __restrict__ tot4, const float* __restrict__ pos4,
                       float* out){
  const float PI_ = (float)(INUM_PAD-INUM);   // 8
  const float PK_ = (float)(KCL_PAD-KCL);     // 8
  float s0=0,s1=0,s2=0,s3=0;
  for(int b=threadIdx.x; b<NU; b+=256){
    s0 += logf(tot4[0*NU+b])       - 10.f*pos4[0*NU+b];
    s1 += logf(tot4[1*NU+b] - PI_) - 10.f*pos4[1*NU+b];
    s2 += logf(tot4[2*NU+b] - PK_) - 10.f*pos4[2*NU+b];
    s3 += logf(tot4[3*NU+b] - PK_) - 10.f*pos4[3*NU+b];
  }
  s0=wred64(s0); s1=wred64(s1); s2=wred64(s2); s3=wred64(s3);
  __shared__ float ls[4][4];
  int lane=threadIdx.x&63, w=threadIdx.x>>6;
  if(lane==0){ ls[w][0]=s0; ls[w][1]=s1; ls[w][2]=s2; ls[w][3]=s3; }
  __syncthreads();
  if(threadIdx.x==0){
    float a=0,b2=0,c=0,d=0;
#pragma unroll
    for(int k=0;k<4;k++){ a+=ls[k][0]; b2+=ls[k][1]; c+=ls[k][2]; d+=ls[k][3]; }
    out[2*NPRED]   = 1e-6f*(a+b2);
    out[2*NPRED+1] = 8e-8f*(c+d);
  }
}

extern "C" void kernel_launch(void* const* d_in, const int* in_sizes, int n_in,
                              void* d_out, int out_size, void* d_ws, size_t ws_size,
                              hipStream_t stream) {
  const float* emb_user = (const float*)d_in[0];
  const float* emb_item = (const float*)d_in[1];
  const float* ucent    = (const float*)d_in[2];
  const float* icent    = (const float*)d_in[3];
  const int* edge_u = (const int*)d_in[4];
  const int* edge_v = (const int*)d_in[5];
  const int* pos_u  = (const int*)d_in[6];
  const int* pos_v  = (const int*)d_in[7];
  const int* neg_u  = (const int*)d_in[8];
  const int* neg_v  = (const int*)d_in[9];
  const int* idx_u  = (const int*)d_in[10];
  const int* idx_i  = (const int*)d_in[11];
  const int* u2c    = (const int*)d_in[12];
  const int* i2c    = (const int*)d_in[13];
  float* out = (float*)d_out;

  char* w = (char*)d_ws;
  auto alloc = [&](size_t bytes)->void*{
    void* p = (void*)w;
    w += (bytes + 255) & ~(size_t)255;
    return p;
  };
  int* cnt_u = (int*)alloc(NU*4);            // contiguous with cnt_i: one memset
  int* cnt_i = (int*)alloc(NI*4);
  int* rp_u  = (int*)alloc((NU+1)*4);
  int* rp_i  = (int*)alloc((NI+1)*4);
  int* cur_u = (int*)alloc(NU*4);
  int* cur_i = (int*)alloc(NI*4);
  int* adj_u = (int*)alloc((size_t)NE*4);
  int* adj_i = (int*)alloc((size_t)NE*4);
  float* inv_u = (float*)alloc(NU*4);
  float* inv_i = (float*)alloc(NI*4);
  float* e_u  = (float*)alloc((size_t)NU*DD*4);
  float* e_i  = (float*)alloc((size_t)NI*DD*4);
  float* h_u  = (float*)alloc((size_t)NU*DD*4);
  float* h_i  = (float*)alloc((size_t)NI*DD*4);
  float* hsA_u = (float*)alloc((size_t)NU*DD*4);
  float* hsA_i = (float*)alloc((size_t)NI*DD*4);
  float* hsB_u = (float*)alloc((size_t)NU*DD*4);
  float* hsB_i = (float*)alloc((size_t)NI*DD*4);
  float* res_u= (float*)alloc((size_t)NU*DD*4);
  float* res_i= (float*)alloc((size_t)NI*DD*4);
  // B-side bf16 buffers: +48 rows slack for depth-1 prefetch overrun
  __hip_bfloat16* ntb_user = (__hip_bfloat16*)alloc((size_t)(UNUM+48)*DD*2);
  __hip_bfloat16* ntb_item = (__hip_bfloat16*)alloc((size_t)(INUM_PAD+48)*DD*2);
  __hip_bfloat16* ncb_u = (__hip_bfloat16*)alloc((size_t)(KCL_PAD+48)*DD*2);
  __hip_bfloat16* ncb_i = (__hip_bfloat16*)alloc((size_t)(KCL_PAD+48)*DD*2);
  __hip_bfloat16* nc_u  = (__hip_bfloat16*)alloc((size_t)NU*DD*2);
  __hip_bfloat16* nc_i  = (__hip_bfloat16*)alloc((size_t)NI*DD*2);
  __hip_bfloat16* npv_u = (__hip_bfloat16*)alloc((size_t)NU*DD*2);
  __hip_bfloat16* npv_i = (__hip_bfloat16*)alloc((size_t)NI*DD*2);
  float* tot4 = (float*)alloc(4*NU*4);
  float* pos4 = (float*)alloc(4*NU*4);

  hipMemsetAsync(cnt_u, 0, 2*NU*4, stream);  // cnt_u + cnt_i contiguous

  k_histnorm<<<HN3, 256, 0, stream>>>(edge_u, edge_v, cnt_u, cnt_i,
                                      emb_user, emb_item, ucent, icent,
                                      ntb_user, ntb_item, ncb_u, ncb_i);
  k_scan<<<2, 1024, 0, stream>>>(cnt_u, rp_u, cur_u, inv_u,
                                 cnt_i, rp_i, cur_i, inv_i, tot4);
  k_fillgather<<<3072, 256, 0, stream>>>(edge_u, edge_v, cur_u, cur_i, adj_u, adj_i,
                                         emb_user, emb_item, idx_u, idx_i,
                                         inv_u, inv_i,
                                         e_u, e_i, res_u, res_i, hsA_u, hsA_i);
  // layer 0: A->B; layer 1: B->A; layer 2 (last): A->(h,res,norms,pos)
  k_conv<<<(NU+NI)/4, 256, 0, stream>>>(rp_i, adj_i, hsA_u, inv_i, h_i, res_i, hsB_i,
                                        rp_u, adj_u, hsA_i, inv_u, h_u, res_u, hsB_u,
                                        e_u, e_i, ucent, icent, idx_u, idx_i, u2c, i2c,
                                        nc_u, nc_i, npv_u, npv_i, pos4, 0);
  k_conv<<<(NU+NI)/4, 256, 0, stream>>>(rp_i, adj_i, hsB_u, inv_i, h_i, res_i, hsA_i,
                                        rp_u, adj_u, hsB_i, inv_u, h_u, res_u, hsA_u,
                                        e_u, e_i, ucent, icent, idx_u, idx_i, u2c, i2c,
                                        nc_u, nc_i, npv_u, npv_i, pos4, 0);
  k_conv<<<(NU+NI)/4, 256, 0, stream>>>(rp_i, adj_i, hsA_u, inv_i, h_i, res_i, hsB_i,
                                        rp_u, adj_u, hsA_i, inv_u, h_u, res_u, hsB_u,
                                        e_u, e_i, ucent, icent, idx_u, idx_i, u2c, i2c,
                                        nc_u, nc_i, npv_u, npv_i, pos4, 1);

  // fused 4-segment exp-sum (z=0..3) + scores (z=4)
  EArg eu_ = { nc_u,  ntb_user, tot4 + 0*NU, UNUM,     512, 98 };
  EArg ei_ = { nc_i,  ntb_item, tot4 + 1*NU, INUM_PAD, 512, 49 };
  EArg ep0 = { npv_u, ncb_u,    tot4 + 2*NU, KCL_PAD,  48,  21 };
  EArg ep1 = { npv_i, ncb_i,    tot4 + 3*NU, KCL_PAD,  48,  21 };
  SArg sc  = { res_u, res_i, pos_u, pos_v, neg_u, neg_v, out };
  k_expsum<<<dim3(EGX,1,5), 256, 0, stream>>>(eu_, ei_, ep0, ep1, sc);

  k_loss<<<1, 256, 0, stream>>>(tot4, pos4, out);
}

// Round 19
// 210.212 us; speedup vs baseline: 1.2042x; 1.0083x over previous
//
#include <hip/hip_runtime.h>
#include <hip/hip_bf16.h>

#define NU 4096
#define NI 4096
#define NE 262144
#define NPRED 65536
#define DD 64
#define KCL 1000
#define UNUM 50000
#define INUM 25000
#define INUM_PAD 25008
#define KCL_PAD 1008

typedef short sh8 __attribute__((ext_vector_type(8)));
typedef float f4 __attribute__((ext_vector_type(4)));

__device__ __forceinline__ float wred64(float x){
#pragma unroll
  for(int m=1;m<64;m<<=1) x += __shfl_xor(x,m);
  return x;
}

__device__ __forceinline__ float fast_exp2(float x){
  return __builtin_amdgcn_exp2f(x);
}

// ---- fused: degree histogram (blocks 0..1023) + static-table norms ----
#define HB 1024
#define HN0 (HB+12500)        // ntb_user  (50000 rows /4)
#define HN1 (HN0+6252)        // ntb_item  (25008 padded /4)
#define HN2 (HN1+252)         // ncb_u     (1008 padded /4)
#define HN3 (HN2+252)         // ncb_i     (1008 padded /4)

__global__ void k_histnorm(const int* __restrict__ eu, const int* __restrict__ ev,
                           int* cu, int* ci,
                           const float* __restrict__ emb_u, const float* __restrict__ emb_i,
                           const float* __restrict__ ucent, const float* __restrict__ icent,
                           __hip_bfloat16* ntb_u, __hip_bfloat16* ntb_i,
                           __hip_bfloat16* ncb_u, __hip_bfloat16* ncb_i){
  int b = blockIdx.x;
  if(b < HB){
    int t = b*256 + threadIdx.x;
    atomicAdd(&cu[eu[t]],1); atomicAdd(&ci[ev[t]],1);
    return;
  }
  const float* in; __hip_bfloat16* outp; int rows; int base;
  if(b < HN0)      { in=emb_u; outp=ntb_u; rows=UNUM; base=HB; }
  else if(b < HN1) { in=emb_i; outp=ntb_i; rows=INUM; base=HN0; }
  else if(b < HN2) { in=ucent; outp=ncb_u; rows=KCL;  base=HN1; }
  else             { in=icent; outp=ncb_i; rows=KCL;  base=HN2; }
  int row = (b-base)*4 + (threadIdx.x>>6);
  int lane = threadIdx.x & 63;
  if(row >= rows){ outp[row*DD + lane] = __float2bfloat16(0.f); return; }
  float v = in[row*DD + lane];
  float s = wred64(v*v);
  float sc = 1.0f / fmaxf(sqrtf(s), 1e-12f);
  outp[row*DD + lane] = __float2bfloat16(v*sc);
}

// ---- exclusive scan over 4096 counts (one block per side) + tot4 zeroing ----
__global__ void k_scan(const int* cnt_u, int* rp_u, int* cur_u, float* inv_u,
                       const int* cnt_i, int* rp_i, int* cur_i, float* inv_i,
                       float* tot4){
  {
    int base = blockIdx.x*8192 + threadIdx.x*8;
#pragma unroll
    for(int k=0;k<8;k++) tot4[base+k] = 0.f;
  }
  const int* cnt = blockIdx.x ? cnt_i : cnt_u;
  int* rp  = blockIdx.x ? rp_i  : rp_u;
  int* cur = blockIdx.x ? cur_i : cur_u;
  float* inv = blockIdx.x ? inv_i : inv_u;
  __shared__ int sdata[1024];
  int tid = threadIdx.x;
  int v[4]; int s = 0;
#pragma unroll
  for(int k=0;k<4;k++){ v[k]=cnt[tid*4+k]; s+=v[k]; }
  sdata[tid]=s; __syncthreads();
  for(int off=1; off<1024; off<<=1){
    int add = (tid>=off)? sdata[tid-off] : 0;
    __syncthreads();
    if(tid>=off) sdata[tid] += add;
    __syncthreads();
  }
  int run = sdata[tid]-s;   // exclusive base
#pragma unroll
  for(int k=0;k<4;k++){
    int idx = tid*4+k;
    rp[idx]=run; cur[idx]=run;
    inv[idx] = 1.0f/sqrtf(fmaxf((float)v[k],1.0f));
    run += v[k];
  }
  if(tid==1023) rp[4096]=run;
}

// ---- fused CSR fill (blocks 0..1023) + gather/init (blocks 1024..3071) ----
__global__ void k_fillgather(const int* __restrict__ eu, const int* __restrict__ ev,
                             int* cur_u, int* cur_i, int* adj_u, int* adj_i,
                             const float* __restrict__ emb_u, const float* __restrict__ emb_i,
                             const int* __restrict__ idx_u, const int* __restrict__ idx_i,
                             const float* __restrict__ inv_u, const float* __restrict__ inv_i,
                             float* e_u, float* e_i, float* res_u, float* res_i,
                             float* hs_u, float* hs_i){
  int b = blockIdx.x;
  if(b < 1024){
    int t = b*256 + threadIdx.x;
    int u=eu[t], v=ev[t];
    adj_u[atomicAdd(&cur_u[u],1)] = v;
    adj_i[atomicAdd(&cur_i[v],1)] = u;
  } else {
    int t = (b-1024)*256 + threadIdx.x;
    const int half = NU*DD;
    if(t < half){
      int r=t>>6;
      float v = emb_u[idx_u[r]*DD + (t&63)];
      e_u[t]=v; res_u[t]=v; hs_u[t]=v*inv_u[r];
    } else {
      int s=t-half; int r=s>>6;
      float v = emb_i[idx_i[r]*DD + (s&63)];
      e_i[s]=v; res_i[s]=v; hs_i[s]=v*inv_i[r];
    }
  }
}

// ---- pull-style conv: 4 waves per block, one node per wave ----
// adj content differs call-to-call (atomic fill order), so adj MUST be read
// through the vector path (coalesced per-lane load + shfl broadcast), never
// scalar s_load (K$ staleness across graph replays = nondeterministic output).
// last=1 (layer 3): fused epilogue computes nc (SC*normalize(h)),
// npv (SC*normalize(e)) and this side's pos4 entries; skips hs_next write.
__global__ void k_conv(const int* __restrict__ rp_i, const int* __restrict__ adj_i,
                       const float* __restrict__ hsu_in, const float* __restrict__ inv_i,
                       float* h_i, float* res_i, float* hsi_out,
                       const int* __restrict__ rp_u, const int* __restrict__ adj_u,
                       const float* __restrict__ hsi_in, const float* __restrict__ inv_u,
                       float* h_u, float* res_u, float* hsu_out,
                       const float* __restrict__ e_u, const float* __restrict__ e_i,
                       const float* __restrict__ ucent, const float* __restrict__ icent,
                       const int* __restrict__ idx_u, const int* __restrict__ idx_i,
                       const int* __restrict__ u2c, const int* __restrict__ i2c,
                       __hip_bfloat16* nc_u, __hip_bfloat16* nc_i,
                       __hip_bfloat16* npv_u, __hip_bfloat16* npv_i,
                       float* pos4, int last){
  int b = blockIdx.x*4 + (threadIdx.x>>6);
  int lane = threadIdx.x & 63;
  const int* rp; const int* adj; const float* srcv; const float* inv;
  float *h, *res, *hso; int node;
  const float* eX; const float* cent; const int* idxX; const int* n2c;
  __hip_bfloat16 *nc, *npv; float *posA, *posB;
  if(b < NI){
    rp=rp_i; adj=adj_i; srcv=hsu_in; inv=inv_i; h=h_i; res=res_i; hso=hsi_out; node=b;
    eX=e_i; cent=icent; idxX=idx_i; n2c=i2c; nc=nc_i; npv=npv_i;
    posA=pos4+1*NU; posB=pos4+3*NU;
  } else {
    node=b-NI; rp=rp_u; adj=adj_u; srcv=hsi_in; inv=inv_u; h=h_u; res=res_u; hso=hsu_out;
    eX=e_u; cent=ucent; idxX=idx_u; n2c=u2c; nc=nc_u; npv=npv_u;
    posA=pos4+0*NU; posB=pos4+2*NU;
  }
  int s=rp[node], e=rp[node+1];
  float acc=0.f;
  for(int base=s; base<e; base+=64){
    int m = e-base;
    int myidx = adj[base + min(lane, m-1)];   // one coalesced vector load / 64 edges
    int kk = min(64, m);
    int k=0;
    for(; k+8<=kk; k+=8){
      int i0=__shfl(myidx,k  ), i1=__shfl(myidx,k+1),
          i2=__shfl(myidx,k+2), i3=__shfl(myidx,k+3),
          i4=__shfl(myidx,k+4), i5=__shfl(myidx,k+5),
          i6=__shfl(myidx,k+6), i7=__shfl(myidx,k+7);
      float v0=srcv[i0*DD+lane], v1=srcv[i1*DD+lane],
            v2=srcv[i2*DD+lane], v3=srcv[i3*DD+lane],
            v4=srcv[i4*DD+lane], v5=srcv[i5*DD+lane],
            v6=srcv[i6*DD+lane], v7=srcv[i7*DD+lane];
      acc += ((v0+v1)+(v2+v3)) + ((v4+v5)+(v6+v7));
    }
    for(; k<kk; k++) acc += srcv[__shfl(myidx,k)*DD+lane];
  }
  float iv = inv[node];
  float outv = acc*iv;
  h[node*DD+lane] = outv;
  res[node*DD+lane] += outv;
  if(!last){
    hso[node*DD+lane] = outv*iv;
    return;
  }
  // ---- fused epilogue (layer 3): norms + pos dots ----
  const float SC = 14.426950408889634f;
  const float eps = 1e-12f;
  float ev = eX[node*DD+lane];
  float hn = wred64(outv*outv);
  float en = wred64(ev*ev);
  float ihn = 1.0f/fmaxf(sqrtf(hn), eps);
  float ien = 1.0f/fmaxf(sqrtf(en), eps);
  nc [node*DD+lane] = __float2bfloat16(outv*(SC*ihn));
  npv[node*DD+lane] = __float2bfloat16(ev  *(SC*ien));
  int c = n2c[idxX[node]];
  float cv = cent[c*DD+lane];
  float he = wred64(outv*ev);
  float cc = wred64(cv*cv);
  float ec = wred64(ev*cv);
  if(lane==0){
    float icn = 1.0f/fmaxf(sqrtf(cc), eps);
    posA[node] = he*ihn*ien;
    posB[node] = ec*ien*icn;
  }
}

// ---- fused MFMA exp-sum (z=0..3) + scores (z=4); 128 A-rows per wave ----
// R16-bench skeleton; inner loop restructured into two t-halves with an
// explicit c[4] array: 8 independent MFMAs issue back-to-back, THEN 16 exps
// stream at trans rate (previous codegen reused one c register -> each t
// serialized mfma->mfma->stall->exp, ~800cy/iter vs ~400 ideal; VGPR=60 was
// the tell). Same loads, same math order per acc element (bitwise identical).
// jchunk=512 -> 1208 working blocks. XCD-pinned decomposition:
// bid -> (g=bid/64, r=bid%64), y=8g+(r&7), x=r>>3.
// z=4 runs the pos/neg score pairs (memory-bound, backfills expsum drain).
// tot[b] += sum_j exp2(dot(A[b],B[j])), A pre-scaled by SC = 10*log2(e).
// B buffers have >=48 rows of slack past nBpad (depth-1 prefetch overrun).
struct EArg {
  const __hip_bfloat16* A; const __hip_bfloat16* B; float* tot;
  int nBpad; int jchunk; int ny;
};
struct SArg {
  const float* res_u; const float* res_i;
  const int* pu; const int* pv; const int* nu; const int* nv; float* out;
};
#define EGX 784

__global__ __launch_bounds__(256,4)
void k_expsum(EArg e0, EArg e1, EArg e2, EArg e3, SArg sc){
  if(blockIdx.z == 4){
    // ---- scores: 16 lanes per pair, grid-stride ----
    const int stride = EGX*256;
    const int limit = 2*NPRED*16;
    for(int t = blockIdx.x*256 + threadIdx.x; t < limit; t += stride){
      int pair = t >> 4;
      int sl = t & 15;
      int a,b;
      if(pair < NPRED){ a=sc.pu[pair]; b=sc.pv[pair]; }
      else { a=sc.nu[pair-NPRED]; b=sc.nv[pair-NPRED]; }
      f4 xu = *(const f4*)(sc.res_u + a*DD + sl*4);
      f4 xv = *(const f4*)(sc.res_i + b*DD + sl*4);
      float x = xu[0]*xv[0] + xu[1]*xv[1] + xu[2]*xv[2] + xu[3]*xv[3];
      x += __shfl_xor(x,1); x += __shfl_xor(x,2);
      x += __shfl_xor(x,4); x += __shfl_xor(x,8);
      if(sl==0) sc.out[pair] = x*(1.0f/16.0f);  // res divided by 4 each side
    }
    return;
  }
  EArg e = (blockIdx.z==0)? e0 : (blockIdx.z==1)? e1 : (blockIdx.z==2)? e2 : e3;
  int bid = blockIdx.x;
  int g = bid >> 6, r6 = bid & 63;
  int y = 8*g + (r6 & 7);
  int x = r6 >> 3;
  if(y >= e.ny) return;
  int wave = threadIdx.x >> 6;
  int lane = threadIdx.x & 63;
  int row0 = (x*4 + wave)*128;
  int j_begin = y*e.jchunk;
  int j_end = min(j_begin + e.jchunk, e.nBpad);
  int r = lane & 15, kq = (lane>>4)*8;

  sh8 a0[8], a1[8];
#pragma unroll
  for(int t=0;t<8;t++){
    const short* ap = (const short*)(e.A + (row0 + t*16 + r)*DD);
    a0[t] = *(const sh8*)(ap + kq);
    a1[t] = *(const sh8*)(ap + kq + 32);
  }
  float acc[8][4];
#pragma unroll
  for(int t=0;t<8;t++)
#pragma unroll
    for(int q=0;q<4;q++) acc[t][q]=0.f;

  const short* bbase = (const short*)e.B;
  const short* bp0 = bbase + (j_begin + r)*DD + kq;
  sh8 b0 = *(const sh8*)(bp0);
  sh8 b1 = *(const sh8*)(bp0 + 32);

#pragma unroll 2
  for(int j0=j_begin; j0<j_end; j0+=16){
    const short* np = bbase + (j0 + 16 + r)*DD + kq;   // prefetch next tile
    sh8 n0 = *(const sh8*)(np);
    sh8 n1 = *(const sh8*)(np + 32);
    // half 1: t = 0..3 — 8 independent MFMAs, then 16 exps
    {
      f4 c[4];
#pragma unroll
      for(int t=0;t<4;t++){
        f4 cc = {0.f,0.f,0.f,0.f};
        cc = __builtin_amdgcn_mfma_f32_16x16x32_bf16(a0[t], b0, cc, 0,0,0);
        c[t] = __builtin_amdgcn_mfma_f32_16x16x32_bf16(a1[t], b1, cc, 0,0,0);
      }
#pragma unroll
      for(int t=0;t<4;t++)
#pragma unroll
        for(int q=0;q<4;q++) acc[t][q] += fast_exp2(c[t][q]);
    }
    // half 2: t = 4..7
    {
      f4 c[4];
#pragma unroll
      for(int t=0;t<4;t++){
        f4 cc = {0.f,0.f,0.f,0.f};
        cc = __builtin_amdgcn_mfma_f32_16x16x32_bf16(a0[t+4], b0, cc, 0,0,0);
        c[t] = __builtin_amdgcn_mfma_f32_16x16x32_bf16(a1[t+4], b1, cc, 0,0,0);
      }
#pragma unroll
      for(int t=0;t<4;t++)
#pragma unroll
        for(int q=0;q<4;q++) acc[t+4][q] += fast_exp2(c[t][q]);
    }
    b0 = n0; b1 = n1;
  }
#pragma unroll
  for(int t=0;t<8;t++){
#pragma unroll
    for(int q=0;q<4;q++){
      float v = acc[t][q];
      v += __shfl_xor(v,1); v += __shfl_xor(v,2);
      v += __shfl_xor(v,4); v += __shfl_xor(v,8);
      if(r==0) atomicAdd(&e.tot[row0 + t*16 + (lane>>4)*4 + q], v);
    }
  }
}

// ---- final losses (pad rows each contributed exp2(0)=1 -> subtract) ----
__global__ void k_loss(const float* __restrict__ tot4, const float* __restrict__ pos4,
                       float* out){
  const float PI_ = (float)(INUM_PAD-INUM);   // 8
  const float PK_ = (float)(KCL_PAD-KCL);     // 8
  float s0=0,s1=0,s2=0,s3=0;
  for(int b=threadIdx.x; b<NU; b+=256){
    s0 += logf(tot4[0*NU+b])       - 10.f*pos4[0*NU+b];
    s1 += logf(tot4[1*NU+b] - PI_) - 10.f*pos4[1*NU+b];
    s2 += logf(tot4[2*NU+b] - PK_) - 10.f*pos4[2*NU+b];
    s3 += logf(tot4[3*NU+b] - PK_) - 10.f*pos4[3*NU+b];
  }
  s0=wred64(s0); s1=wred64(s1); s2=wred64(s2); s3=wred64(s3);
  __shared__ float ls[4][4];
  int lane=threadIdx.x&63, w=threadIdx.x>>6;
  if(lane==0){ ls[w][0]=s0; ls[w][1]=s1; ls[w][2]=s2; ls[w][3]=s3; }
  __syncthreads();
  if(threadIdx.x==0){
    float a=0,b2=0,c=0,d=0;
#pragma unroll
    for(int k=0;k<4;k++){ a+=ls[k][0]; b2+=ls[k][1]; c+=ls[k][2]; d+=ls[k][3]; }
    out[2*NPRED]   = 1e-6f*(a+b2);
    out[2*NPRED+1] = 8e-8f*(c+d);
  }
}

extern "C" void kernel_launch(void* const* d_in, const int* in_sizes, int n_in,
                              void* d_out, int out_size, void* d_ws, size_t ws_size,
                              hipStream_t stream) {
  const float* emb_user = (const float*)d_in[0];
  const float* emb_item = (const float*)d_in[1];
  const float* ucent    = (const float*)d_in[2];
  const float* icent    = (const float*)d_in[3];
  const int* edge_u = (const int*)d_in[4];
  const int* edge_v = (const int*)d_in[5];
  const int* pos_u  = (const int*)d_in[6];
  const int* pos_v  = (const int*)d_in[7];
  const int* neg_u  = (const int*)d_in[8];
  const int* neg_v  = (const int*)d_in[9];
  const int* idx_u  = (const int*)d_in[10];
  const int* idx_i  = (const int*)d_in[11];
  const int* u2c    = (const int*)d_in[12];
  const int* i2c    = (const int*)d_in[13];
  float* out = (float*)d_out;

  char* w = (char*)d_ws;
  auto alloc = [&](size_t bytes)->void*{
    void* p = (void*)w;
    w += (bytes + 255) & ~(size_t)255;
    return p;
  };
  int* cnt_u = (int*)alloc(NU*4);            // contiguous with cnt_i: one memset
  int* cnt_i = (int*)alloc(NI*4);
  int* rp_u  = (int*)alloc((NU+1)*4);
  int* rp_i  = (int*)alloc((NI+1)*4);
  int* cur_u = (int*)alloc(NU*4);
  int* cur_i = (int*)alloc(NI*4);
  int* adj_u = (int*)alloc((size_t)NE*4);
  int* adj_i = (int*)alloc((size_t)NE*4);
  float* inv_u = (float*)alloc(NU*4);
  float* inv_i = (float*)alloc(NI*4);
  float* e_u  = (float*)alloc((size_t)NU*DD*4);
  float* e_i  = (float*)alloc((size_t)NI*DD*4);
  float* h_u  = (float*)alloc((size_t)NU*DD*4);
  float* h_i  = (float*)alloc((size_t)NI*DD*4);
  float* hsA_u = (float*)alloc((size_t)NU*DD*4);
  float* hsA_i = (float*)alloc((size_t)NI*DD*4);
  float* hsB_u = (float*)alloc((size_t)NU*DD*4);
  float* hsB_i = (float*)alloc((size_t)NI*DD*4);
  float* res_u= (float*)alloc((size_t)NU*DD*4);
  float* res_i= (float*)alloc((size_t)NI*DD*4);
  // B-side bf16 buffers: +48 rows slack for depth-1 prefetch overrun
  __hip_bfloat16* ntb_user = (__hip_bfloat16*)alloc((size_t)(UNUM+48)*DD*2);
  __hip_bfloat16* ntb_item = (__hip_bfloat16*)alloc((size_t)(INUM_PAD+48)*DD*2);
  __hip_bfloat16* ncb_u = (__hip_bfloat16*)alloc((size_t)(KCL_PAD+48)*DD*2);
  __hip_bfloat16* ncb_i = (__hip_bfloat16*)alloc((size_t)(KCL_PAD+48)*DD*2);
  __hip_bfloat16* nc_u  = (__hip_bfloat16*)alloc((size_t)NU*DD*2);
  __hip_bfloat16* nc_i  = (__hip_bfloat16*)alloc((size_t)NI*DD*2);
  __hip_bfloat16* npv_u = (__hip_bfloat16*)alloc((size_t)NU*DD*2);
  __hip_bfloat16* npv_i = (__hip_bfloat16*)alloc((size_t)NI*DD*2);
  float* tot4 = (float*)alloc(4*NU*4);
  float* pos4 = (float*)alloc(4*NU*4);

  hipMemsetAsync(cnt_u, 0, 2*NU*4, stream);  // cnt_u + cnt_i contiguous

  k_histnorm<<<HN3, 256, 0, stream>>>(edge_u, edge_v, cnt_u, cnt_i,
                                      emb_user, emb_item, ucent, icent,
                                      ntb_user, ntb_item, ncb_u, ncb_i);
  k_scan<<<2, 1024, 0, stream>>>(cnt_u, rp_u, cur_u, inv_u,
                                 cnt_i, rp_i, cur_i, inv_i, tot4);
  k_fillgather<<<3072, 256, 0, stream>>>(edge_u, edge_v, cur_u, cur_i, adj_u, adj_i,
                                         emb_user, emb_item, idx_u, idx_i,
                                         inv_u, inv_i,
                                         e_u, e_i, res_u, res_i, hsA_u, hsA_i);
  // layer 0: A->B; layer 1: B->A; layer 2 (last): A->(h,res,norms,pos)
  k_conv<<<(NU+NI)/4, 256, 0, stream>>>(rp_i, adj_i, hsA_u, inv_i, h_i, res_i, hsB_i,
                                        rp_u, adj_u, hsA_i, inv_u, h_u, res_u, hsB_u,
                                        e_u, e_i, ucent, icent, idx_u, idx_i, u2c, i2c,
                                        nc_u, nc_i, npv_u, npv_i, pos4, 0);
  k_conv<<<(NU+NI)/4, 256, 0, stream>>>(rp_i, adj_i, hsB_u, inv_i, h_i, res_i, hsA_i,
                                        rp_u, adj_u, hsB_i, inv_u, h_u, res_u, hsA_u,
                                        e_u, e_i, ucent, icent, idx_u, idx_i, u2c, i2c,
                                        nc_u, nc_i, npv_u, npv_i, pos4, 0);
  k_conv<<<(NU+NI)/4, 256, 0, stream>>>(rp_i, adj_i, hsA_u, inv_i, h_i, res_i, hsB_i,
                                        rp_u, adj_u, hsA_i, inv_u, h_u, res_u, hsB_u,
                                        e_u, e_i, ucent, icent, idx_u, idx_i, u2c, i2c,
                                        nc_u, nc_i, npv_u, npv_i, pos4, 1);

  // fused 4-segment exp-sum (z=0..3) + scores (z=4)
  EArg eu_ = { nc_u,  ntb_user, tot4 + 0*NU, UNUM,     512, 98 };
  EArg ei_ = { nc_i,  ntb_item, tot4 + 1*NU, INUM_PAD, 512, 49 };
  EArg ep0 = { npv_u, ncb_u,    tot4 + 2*NU, KCL_PAD,  48,  21 };
  EArg ep1 = { npv_i, ncb_i,    tot4 + 3*NU, KCL_PAD,  48,  21 };
  SArg sc  = { res_u, res_i, pos_u, pos_v, neg_u, neg_v, out };
  k_expsum<<<dim3(EGX,1,5), 256, 0, stream>>>(eu_, ei_, ep0, ep1, sc);

  k_loss<<<1, 256, 0, stream>>>(tot4, pos4, out);
}